// Round 5
// baseline (1273.457 us; speedup 1.0000x reference)
//
#include <hip/hip_runtime.h>
#include <hip/hip_bf16.h>
#include <math.h>

#define S_LEN 2048
#define NHEADS 71
#define HDIM 64
#define HSZ (NHEADS * HDIM)        // 4544
#define QKVN ((NHEADS + 2) * HDIM) // 4672

typedef unsigned short u16;
typedef __attribute__((ext_vector_type(8))) short short8;
typedef __attribute__((ext_vector_type(4))) float floatx4;

__device__ __forceinline__ float bf2f(u16 v) {
    unsigned u = ((unsigned)v) << 16;
    return __builtin_bit_cast(float, u);
}
__device__ __forceinline__ u16 f2bf(float f) {
    unsigned u = __builtin_bit_cast(unsigned, f);
    u += 0x7fff + ((u >> 16) & 1);   // RNE
    return (u16)(u >> 16);
}

// dtype-flexible loaders (fp32 -> bf16 convert on the fly)
__device__ __forceinline__ u16 ld_bf(const u16* p)   { return *p; }
__device__ __forceinline__ u16 ld_bf(const float* p) { return f2bf(*p); }
__device__ __forceinline__ void ld8_bf(const u16* p, u16* dst) {
    *(short8*)dst = *(const short8*)p;
}
__device__ __forceinline__ void ld8_bf(const float* p, u16* dst) {
    floatx4 a = *(const floatx4*)p;
    floatx4 b = *(const floatx4*)(p + 4);
#pragma unroll
    for (int i = 0; i < 4; ++i) { dst[i] = f2bf(a[i]); dst[4 + i] = f2bf(b[i]); }
}
// dtype-flexible C store (fp32 accum -> bf16 or fp32)
__device__ __forceinline__ void st_c(u16* p, float v)   { *p = f2bf(v); }
__device__ __forceinline__ void st_c(float* p, float v) { *p = v; }

// ---------------------------------------------------------------------------
// Generic GEMM: C[M,N] = A[M,K] @ B[K,N], fp32 accum. A/B fp32 or bf16;
// C bf16 or fp32. 64x64 tile, BK=32, 4 waves each owning a 32x32 quadrant.
// ---------------------------------------------------------------------------
template <typename TA, typename TB, typename TC>
__global__ __launch_bounds__(256) void gemm64(const TA* __restrict__ A,
                                              const TB* __restrict__ B,
                                              TC* __restrict__ C,
                                              int M, int K, int N)
{
    __shared__ u16 As[64][40];   // stride 40 elts: 16B-aligned, <=2-way bank alias
    __shared__ u16 Bs[64][40];   // transposed: [n][k]

    const int tid  = threadIdx.x;
    const int bm   = blockIdx.y * 64;
    const int bn   = blockIdx.x * 64;
    const int lane = tid & 63;
    const int wid  = tid >> 6;
    const int l15  = lane & 15;
    const int quad = lane >> 4;
    const int wm   = (wid >> 1) * 32;
    const int wn   = (wid & 1) * 32;

    floatx4 acc00 = {0.f,0.f,0.f,0.f}, acc01 = {0.f,0.f,0.f,0.f};
    floatx4 acc10 = {0.f,0.f,0.f,0.f}, acc11 = {0.f,0.f,0.f,0.f};

    const int arow = tid >> 2;
    const int acol = (tid & 3) * 8;
    const int bnn  = tid & 63;
    const int bk0  = (tid >> 6) * 8;

    const TA* Ap = A + (size_t)(bm + arow) * K + acol;

    for (int kb = 0; kb < K; kb += 32) {
        u16 av[8];
        ld8_bf(Ap, av);
        Ap += 32;
        const TB* Bp = B + (size_t)(kb + bk0) * N + bn + bnn;
        u16 bv[8];
#pragma unroll
        for (int j = 0; j < 8; ++j) bv[j] = ld_bf(Bp + (size_t)j * N);

        *(short8*)&As[arow][acol] = *(short8*)&av[0];
        *(short8*)&Bs[bnn][bk0]   = *(short8*)&bv[0];
        __syncthreads();

        short8 a0 = *(const short8*)&As[wm + l15][quad * 8];
        short8 a1 = *(const short8*)&As[wm + 16 + l15][quad * 8];
        short8 b0 = *(const short8*)&Bs[wn + l15][quad * 8];
        short8 b1 = *(const short8*)&Bs[wn + 16 + l15][quad * 8];

        acc00 = __builtin_amdgcn_mfma_f32_16x16x32_bf16(a0, b0, acc00, 0, 0, 0);
        acc01 = __builtin_amdgcn_mfma_f32_16x16x32_bf16(a0, b1, acc01, 0, 0, 0);
        acc10 = __builtin_amdgcn_mfma_f32_16x16x32_bf16(a1, b0, acc10, 0, 0, 0);
        acc11 = __builtin_amdgcn_mfma_f32_16x16x32_bf16(a1, b1, acc11, 0, 0, 0);
        __syncthreads();
    }

    // C/D layout: col = lane&15, row = quad*4 + r
#pragma unroll
    for (int r = 0; r < 4; ++r) {
        int row0 = bm + wm + quad * 4 + r;
        int row1 = row0 + 16;
        int col0 = bn + wn + l15;
        st_c(C + (size_t)row0 * N + col0,      acc00[r]);
        st_c(C + (size_t)row0 * N + col0 + 16, acc01[r]);
        st_c(C + (size_t)row1 * N + col0,      acc10[r]);
        st_c(C + (size_t)row1 * N + col0 + 16, acc11[r]);
    }
}

// ---------------------------------------------------------------------------
// RoPE for K + copy of V out of the fused QKV buffer.
// ---------------------------------------------------------------------------
__global__ void rope_kv(const u16* __restrict__ qkv,
                        u16* __restrict__ Kr,
                        u16* __restrict__ Vo)
{
    int idx = blockIdx.x * 256 + threadIdx.x;  // over S_LEN * 128
    int s = idx >> 7;
    int c = idx & 127;
    if (c < HDIM) {
        int d = c;
        float x  = bf2f(qkv[(size_t)s * QKVN + HSZ + d]);
        int dp   = (d < 32) ? d + 32 : d - 32;
        float xp = bf2f(qkv[(size_t)s * QKVN + HSZ + dp]);
        float rot = (d < 32) ? -xp : xp;
        float invf = expf(-(float)(d & 31) * 0.28782313662425572f);
        float ang  = (float)s * invf;
        float o = x * cosf(ang) + rot * sinf(ang);
        Kr[(size_t)s * HDIM + d] = f2bf(o);
    } else {
        int d = c - HDIM;
        Vo[(size_t)s * HDIM + d] = qkv[(size_t)s * QKVN + (NHEADS + 1) * HDIM + d];
    }
}

// ---------------------------------------------------------------------------
// Fused causal attention (MQA), flash-style online softmax. MFMA.
// Block = (q-tile of 64 rows, head). 4 waves, each owns 16 q rows.
// (numerics evidenced correct by R2==R3 bit-match)
// ---------------------------------------------------------------------------
__global__ __launch_bounds__(256) void attn_fused(const u16* __restrict__ qkv,
                                                  const u16* __restrict__ Kr,
                                                  const u16* __restrict__ V,
                                                  u16* __restrict__ O)
{
    __shared__ u16 Kt[64][72];      // [t][d]
    __shared__ u16 Vt[64][72];      // [d][t] (transposed)
    __shared__ u16 Ps[4][16][72];   // wave-private P tiles [s][t]

    const int tid  = threadIdx.x;
    const int qt   = blockIdx.x;
    const int h    = blockIdx.y;
    const int qs   = qt * 64;
    const int w    = tid >> 6;
    const int lane = tid & 63;
    const int l15  = lane & 15;
    const int quad = lane >> 4;

    // ---- Q fragments with fused RoPE + 0.125 scale ----
    const int srow_a = qs + w * 16 + l15;
    const u16* qp = qkv + (size_t)srow_a * QKVN + h * HDIM;
    short8 r0 = *(const short8*)(qp + quad * 8);
    short8 r1 = *(const short8*)(qp + 32 + quad * 8);
    short8 qf0, qf1;
#pragma unroll
    for (int j = 0; j < 8; ++j) {
        int d0 = quad * 8 + j;
        float invf = expf(-(float)d0 * 0.28782313662425572f);
        float ang  = (float)srow_a * invf;
        float cs = cosf(ang), sn = sinf(ang);
        float x0 = bf2f((u16)r0[j]), x1 = bf2f((u16)r1[j]);
        qf0[j] = (short)f2bf((x0 * cs - x1 * sn) * 0.125f);
        qf1[j] = (short)f2bf((x1 * cs + x0 * sn) * 0.125f);
    }

    floatx4 o0 = {0.f,0.f,0.f,0.f}, o1 = {0.f,0.f,0.f,0.f};
    floatx4 o2 = {0.f,0.f,0.f,0.f}, o3 = {0.f,0.f,0.f,0.f};
    float m_prev[4] = {-1e30f, -1e30f, -1e30f, -1e30f};
    float l_prev[4] = {0.f, 0.f, 0.f, 0.f};

    const int srow_c = qs + w * 16 + quad * 4;

    for (int kt = 0; kt <= qt; ++kt) {
        __syncthreads();
        {   // stage K tile [t][d]
            int trow = tid >> 2, ch = (tid & 3) * 16;
            const u16* kp = Kr + (size_t)(kt * 64 + trow) * HDIM + ch;
            *(short8*)&Kt[trow][ch]     = *(const short8*)(kp);
            *(short8*)&Kt[trow][ch + 8] = *(const short8*)(kp + 8);
        }
        {   // stage V tile transposed [d][t]
            int t = tid & 63, dg = (tid >> 6) * 16;
            const u16* vp = V + (size_t)(kt * 64 + t) * HDIM + dg;
            u16 tmp[16];
            *(short8*)&tmp[0] = *(const short8*)(vp);
            *(short8*)&tmp[8] = *(const short8*)(vp + 8);
#pragma unroll
            for (int j = 0; j < 16; ++j) Vt[dg + j][t] = tmp[j];
        }
        __syncthreads();

        floatx4 sc0 = {0.f,0.f,0.f,0.f}, sc1 = {0.f,0.f,0.f,0.f};
        floatx4 sc2 = {0.f,0.f,0.f,0.f}, sc3 = {0.f,0.f,0.f,0.f};
        {
            short8 ka, kb;
            ka = *(const short8*)&Kt[l15][quad * 8];
            kb = *(const short8*)&Kt[l15][32 + quad * 8];
            sc0 = __builtin_amdgcn_mfma_f32_16x16x32_bf16(qf0, ka, sc0, 0, 0, 0);
            sc0 = __builtin_amdgcn_mfma_f32_16x16x32_bf16(qf1, kb, sc0, 0, 0, 0);
            ka = *(const short8*)&Kt[16 + l15][quad * 8];
            kb = *(const short8*)&Kt[16 + l15][32 + quad * 8];
            sc1 = __builtin_amdgcn_mfma_f32_16x16x32_bf16(qf0, ka, sc1, 0, 0, 0);
            sc1 = __builtin_amdgcn_mfma_f32_16x16x32_bf16(qf1, kb, sc1, 0, 0, 0);
            ka = *(const short8*)&Kt[32 + l15][quad * 8];
            kb = *(const short8*)&Kt[32 + l15][32 + quad * 8];
            sc2 = __builtin_amdgcn_mfma_f32_16x16x32_bf16(qf0, ka, sc2, 0, 0, 0);
            sc2 = __builtin_amdgcn_mfma_f32_16x16x32_bf16(qf1, kb, sc2, 0, 0, 0);
            ka = *(const short8*)&Kt[48 + l15][quad * 8];
            kb = *(const short8*)&Kt[48 + l15][32 + quad * 8];
            sc3 = __builtin_amdgcn_mfma_f32_16x16x32_bf16(qf0, ka, sc3, 0, 0, 0);
            sc3 = __builtin_amdgcn_mfma_f32_16x16x32_bf16(qf1, kb, sc3, 0, 0, 0);
        }

        if (kt == qt) {
            int tbase = kt * 64 + l15;
#pragma unroll
            for (int r = 0; r < 4; ++r) {
                int srow = srow_c + r;
                if (tbase      > srow) sc0[r] = -1e30f;
                if (tbase + 16 > srow) sc1[r] = -1e30f;
                if (tbase + 32 > srow) sc2[r] = -1e30f;
                if (tbase + 48 > srow) sc3[r] = -1e30f;
            }
        }

        float mnew[4], al[4];
#pragma unroll
        for (int r = 0; r < 4; ++r) {
            float t0 = fmaxf(fmaxf(sc0[r], sc1[r]), fmaxf(sc2[r], sc3[r]));
            t0 = fmaxf(t0, __shfl_xor(t0, 1, 64));
            t0 = fmaxf(t0, __shfl_xor(t0, 2, 64));
            t0 = fmaxf(t0, __shfl_xor(t0, 4, 64));
            t0 = fmaxf(t0, __shfl_xor(t0, 8, 64));
            mnew[r] = fmaxf(m_prev[r], t0);
            al[r]   = __expf(m_prev[r] - mnew[r]);
        }
#pragma unroll
        for (int r = 0; r < 4; ++r) {
            float p0 = __expf(sc0[r] - mnew[r]);
            float p1 = __expf(sc1[r] - mnew[r]);
            float p2 = __expf(sc2[r] - mnew[r]);
            float p3 = __expf(sc3[r] - mnew[r]);
            Ps[w][quad * 4 + r][l15]      = f2bf(p0);
            Ps[w][quad * 4 + r][16 + l15] = f2bf(p1);
            Ps[w][quad * 4 + r][32 + l15] = f2bf(p2);
            Ps[w][quad * 4 + r][48 + l15] = f2bf(p3);
            float ls = p0 + p1 + p2 + p3;
            ls += __shfl_xor(ls, 1, 64);
            ls += __shfl_xor(ls, 2, 64);
            ls += __shfl_xor(ls, 4, 64);
            ls += __shfl_xor(ls, 8, 64);
            l_prev[r] = l_prev[r] * al[r] + ls;
            o0[r] *= al[r]; o1[r] *= al[r]; o2[r] *= al[r]; o3[r] *= al[r];
        }

        {
            short8 p0 = *(const short8*)&Ps[w][l15][quad * 8];
            short8 p1 = *(const short8*)&Ps[w][l15][32 + quad * 8];
            short8 v0, v1;
            v0 = *(const short8*)&Vt[l15][quad * 8];
            v1 = *(const short8*)&Vt[l15][32 + quad * 8];
            o0 = __builtin_amdgcn_mfma_f32_16x16x32_bf16(p0, v0, o0, 0, 0, 0);
            o0 = __builtin_amdgcn_mfma_f32_16x16x32_bf16(p1, v1, o0, 0, 0, 0);
            v0 = *(const short8*)&Vt[16 + l15][quad * 8];
            v1 = *(const short8*)&Vt[16 + l15][32 + quad * 8];
            o1 = __builtin_amdgcn_mfma_f32_16x16x32_bf16(p0, v0, o1, 0, 0, 0);
            o1 = __builtin_amdgcn_mfma_f32_16x16x32_bf16(p1, v1, o1, 0, 0, 0);
            v0 = *(const short8*)&Vt[32 + l15][quad * 8];
            v1 = *(const short8*)&Vt[32 + l15][32 + quad * 8];
            o2 = __builtin_amdgcn_mfma_f32_16x16x32_bf16(p0, v0, o2, 0, 0, 0);
            o2 = __builtin_amdgcn_mfma_f32_16x16x32_bf16(p1, v1, o2, 0, 0, 0);
            v0 = *(const short8*)&Vt[48 + l15][quad * 8];
            v1 = *(const short8*)&Vt[48 + l15][32 + quad * 8];
            o3 = __builtin_amdgcn_mfma_f32_16x16x32_bf16(p0, v0, o3, 0, 0, 0);
            o3 = __builtin_amdgcn_mfma_f32_16x16x32_bf16(p1, v1, o3, 0, 0, 0);
        }

#pragma unroll
        for (int r = 0; r < 4; ++r) m_prev[r] = mnew[r];
    }

#pragma unroll
    for (int r = 0; r < 4; ++r) {
        float inv = 1.0f / l_prev[r];
        int row = srow_c + r;
        u16* op = O + (size_t)row * HSZ + h * HDIM;
        op[l15]      = f2bf(o0[r] * inv);
        op[16 + l15] = f2bf(o1[r] * inv);
        op[32 + l15] = f2bf(o2[r] * inv);
        op[48 + l15] = f2bf(o3[r] * inv);
    }
}

// ---------------------------------------------------------------------------
extern "C" void kernel_launch(void* const* d_in, const int* in_sizes, int n_in,
                              void* d_out, int out_size, void* d_ws, size_t ws_size,
                              hipStream_t stream)
{
    // Robust input dispatch by element count (all four are distinct).
    const float* x       = (const float*)d_in[0];   // 2048*4544  = 9306112
    const float* qkv_w   = (const float*)d_in[2];   // 4544*4672  = 21229568
    const float* dense_w = (const float*)d_in[3];   // 4544*4544  = 20647936
    for (int i = 0; i < n_in; ++i) {
        if (in_sizes[i] == S_LEN * HSZ)      x       = (const float*)d_in[i];
        else if (in_sizes[i] == HSZ * QKVN)  qkv_w   = (const float*)d_in[i];
        else if (in_sizes[i] == HSZ * HSZ)   dense_w = (const float*)d_in[i];
        // S_LEN*S_LEN = attention_mask: causal, synthesized in-kernel
    }
    float* out = (float*)d_out;                     // fp32 output (per reference dtype)

    u16* qkv = (u16*)d_ws;                          // 2048*4672 bf16
    u16* kr  = qkv + (size_t)S_LEN * QKVN;          // 2048*64
    u16* vb  = kr  + (size_t)S_LEN * HDIM;          // 2048*64
    u16* at  = vb  + (size_t)S_LEN * HDIM;          // 2048*4544

    gemm64<float, float, u16><<<dim3(QKVN / 64, S_LEN / 64), 256, 0, stream>>>(
        x, qkv_w, qkv, S_LEN, HSZ, QKVN);
    rope_kv<<<(S_LEN * 2 * HDIM) / 256, 256, 0, stream>>>(qkv, kr, vb);
    attn_fused<<<dim3(S_LEN / 64, NHEADS), 256, 0, stream>>>(qkv, kr, vb, at);
    gemm64<u16, float, float><<<dim3(HSZ / 64, S_LEN / 64), 256, 0, stream>>>(
        at, dense_w, out, S_LEN, HSZ, HSZ);
}

// Round 6
// 909.595 us; speedup vs baseline: 1.4000x; 1.4000x over previous
//
#include <hip/hip_runtime.h>
#include <hip/hip_bf16.h>
#include <math.h>

#define S_LEN 2048
#define NHEADS 71
#define HDIM 64
#define HSZ (NHEADS * HDIM)        // 4544
#define QKVN ((NHEADS + 2) * HDIM) // 4672
#define QKVP 4736                  // QKVN padded to 128
#define DNP  4608                  // HSZ padded to 128

typedef unsigned short u16;
typedef __attribute__((ext_vector_type(8))) short short8;
typedef __attribute__((ext_vector_type(4))) float floatx4;

__device__ __forceinline__ float bf2f(u16 v) {
    unsigned u = ((unsigned)v) << 16;
    return __builtin_bit_cast(float, u);
}
__device__ __forceinline__ u16 f2bf(float f) {
    unsigned u = __builtin_bit_cast(unsigned, f);
    u += 0x7fff + ((u >> 16) & 1);   // RNE
    return (u16)(u >> 16);
}

// async global->LDS, 16B per lane. LDS dest must be wave-uniform base;
// HW writes lane's data at base + lane*16 (m97/m104 semantics).
__device__ __forceinline__ void async16(const u16* g, u16* l) {
    __builtin_amdgcn_global_load_lds(
        (const __attribute__((address_space(1))) void*)g,
        (__attribute__((address_space(3))) void*)l,
        16, 0, 0);
}

// dtype-flexible loaders for the fallback path
__device__ __forceinline__ u16 ld_bf(const u16* p)   { return *p; }
__device__ __forceinline__ u16 ld_bf(const float* p) { return f2bf(*p); }
__device__ __forceinline__ void ld8_bf(const u16* p, u16* dst) {
    *(short8*)dst = *(const short8*)p;
}
__device__ __forceinline__ void ld8_bf(const float* p, u16* dst) {
    floatx4 a = *(const floatx4*)p;
    floatx4 b = *(const floatx4*)(p + 4);
#pragma unroll
    for (int i = 0; i < 4; ++i) { dst[i] = f2bf(a[i]); dst[4 + i] = f2bf(b[i]); }
}
__device__ __forceinline__ void st_c(u16* p, float v)   { *p = f2bf(v); }
__device__ __forceinline__ void st_c(float* p, float v) { *p = v; }

// ===========================================================================
// FAST PATH
// ===========================================================================

// fp32 -> bf16 elementwise (n divisible by 8)
__global__ __launch_bounds__(256) void convert_bf16(const float* __restrict__ src,
                                                    u16* __restrict__ dst, int n)
{
    int i = (blockIdx.x * 256 + threadIdx.x) * 8;
    if (i >= n) return;
    floatx4 a = *(const floatx4*)(src + i);
    floatx4 b = *(const floatx4*)(src + i + 4);
    u16 o[8];
#pragma unroll
    for (int j = 0; j < 4; ++j) { o[j] = f2bf(a[j]); o[4 + j] = f2bf(b[j]); }
    *(short8*)(dst + i) = *(short8*)&o[0];
}

// fp32 src[K][Ns]  ->  bf16 dst[Np][K] (transposed, rows n>=Ns zero-padded)
__global__ __launch_bounds__(256) void conv_transpose(const float* __restrict__ src,
                                                      u16* __restrict__ dst,
                                                      int K, int Ns)
{
    __shared__ float t[32][33];
    const int k0 = blockIdx.x * 32, n0 = blockIdx.y * 32;
    const int tx = threadIdx.x & 31, ty = threadIdx.x >> 5;   // ty 0..7
#pragma unroll
    for (int i = 0; i < 4; ++i) {
        int r = ty + i * 8;
        int n = n0 + tx;
        t[r][tx] = (n < Ns) ? src[(size_t)(k0 + r) * Ns + n] : 0.f;
    }
    __syncthreads();
#pragma unroll
    for (int i = 0; i < 4; ++i) {
        int rr = ty + i * 8;   // n offset within tile
        dst[(size_t)(n0 + rr) * K + k0 + tx] = f2bf(t[tx][rr]);
    }
}

// m97-structure GEMM: C[M,N] = A[M,K] @ Bt[N,K]^T. bf16 in, fp32 accum.
// BM=BN=128, BK=64, 256 thr = 4 waves, each wave a 64x64 quadrant (4x4 MFMA).
// A,Bt staged by global_load_lds dwordx4 into unpadded [128][64] LDS.
template <bool STORE_F32>
__global__ __launch_bounds__(256) void gemm128(const u16* __restrict__ A,   // [M][K]
                                               const u16* __restrict__ Bt,  // [Np][K]
                                               void* __restrict__ Cv,
                                               int M, int K, int Np, int Nreal)
{
    __shared__ u16 As[128 * 64];
    __shared__ u16 Bs[128 * 64];

    const int tid  = threadIdx.x;
    const int w    = tid >> 6, lane = tid & 63;
    const int l15  = lane & 15, quad = lane >> 4;
    const int bm   = blockIdx.y * 128, bn = blockIdx.x * 128;
    const int wm   = (w >> 1) * 64, wn = (w & 1) * 64;

    floatx4 acc[4][4] = {};

    // staging: wave w covers rows [w*32, w*32+32); per inst: 8 rows x 64 cols
    const int srow = w * 32 + (lane >> 3);
    const int scol = (lane & 7) * 8;
    const u16* Ab = A  + (size_t)(bm + srow) * K + scol;
    const u16* Bb = Bt + (size_t)(bn + srow) * K + scol;
    u16* As_w = &As[(w * 32) * 64];   // wave-uniform LDS bases
    u16* Bs_w = &Bs[(w * 32) * 64];

    for (int kb = 0; kb < K; kb += 64) {
#pragma unroll
        for (int i = 0; i < 4; ++i)
            async16(Ab + (size_t)(i * 8) * K + kb, As_w + i * 8 * 64);
#pragma unroll
        for (int i = 0; i < 4; ++i)
            async16(Bb + (size_t)(i * 8) * K + kb, Bs_w + i * 8 * 64);
        __syncthreads();

#pragma unroll
        for (int kk = 0; kk < 2; ++kk) {
            short8 af[4], bfr[4];
#pragma unroll
            for (int t = 0; t < 4; ++t) {
                af[t]  = *(const short8*)&As[(wm + t * 16 + l15) * 64 + kk * 32 + quad * 8];
                bfr[t] = *(const short8*)&Bs[(wn + t * 16 + l15) * 64 + kk * 32 + quad * 8];
            }
#pragma unroll
            for (int mi = 0; mi < 4; ++mi)
#pragma unroll
                for (int ni = 0; ni < 4; ++ni)
                    acc[mi][ni] = __builtin_amdgcn_mfma_f32_16x16x32_bf16(
                        af[mi], bfr[ni], acc[mi][ni], 0, 0, 0);
        }
        __syncthreads();
    }

    // C/D: col = lane&15, row = quad*4 + r (verified R5)
    if (STORE_F32) {
        float* C = (float*)Cv;
#pragma unroll
        for (int mi = 0; mi < 4; ++mi)
#pragma unroll
            for (int ni = 0; ni < 4; ++ni) {
                int col  = bn + wn + ni * 16 + l15;
                int row0 = bm + wm + mi * 16 + quad * 4;
                if (col < Nreal) {
#pragma unroll
                    for (int r = 0; r < 4; ++r)
                        C[(size_t)(row0 + r) * Nreal + col] = acc[mi][ni][r];
                }
            }
    } else {
        u16* C = (u16*)Cv;
#pragma unroll
        for (int mi = 0; mi < 4; ++mi)
#pragma unroll
            for (int ni = 0; ni < 4; ++ni) {
                int col  = bn + wn + ni * 16 + l15;
                int row0 = bm + wm + mi * 16 + quad * 4;
#pragma unroll
                for (int r = 0; r < 4; ++r)
                    C[(size_t)(row0 + r) * Np + col] = f2bf(acc[mi][ni][r]);
            }
    }
}

// ===========================================================================
// FALLBACK PATH (R5's verified gemm64; used only if ws_size is too small)
// ===========================================================================
template <typename TA, typename TB, typename TC>
__global__ __launch_bounds__(256) void gemm64(const TA* __restrict__ A,
                                              const TB* __restrict__ B,
                                              TC* __restrict__ C,
                                              int M, int K, int N)
{
    __shared__ u16 As[64][40];
    __shared__ u16 Bs[64][40];

    const int tid  = threadIdx.x;
    const int bm   = blockIdx.y * 64;
    const int bn   = blockIdx.x * 64;
    const int lane = tid & 63;
    const int wid  = tid >> 6;
    const int l15  = lane & 15;
    const int quad = lane >> 4;
    const int wm   = (wid >> 1) * 32;
    const int wn   = (wid & 1) * 32;

    floatx4 acc00 = {0.f,0.f,0.f,0.f}, acc01 = {0.f,0.f,0.f,0.f};
    floatx4 acc10 = {0.f,0.f,0.f,0.f}, acc11 = {0.f,0.f,0.f,0.f};

    const int arow = tid >> 2;
    const int acol = (tid & 3) * 8;
    const int bnn  = tid & 63;
    const int bk0  = (tid >> 6) * 8;

    const TA* Ap = A + (size_t)(bm + arow) * K + acol;

    for (int kb = 0; kb < K; kb += 32) {
        u16 av[8];
        ld8_bf(Ap, av);
        Ap += 32;
        const TB* Bp = B + (size_t)(kb + bk0) * N + bn + bnn;
        u16 bv[8];
#pragma unroll
        for (int j = 0; j < 8; ++j) bv[j] = ld_bf(Bp + (size_t)j * N);

        *(short8*)&As[arow][acol] = *(short8*)&av[0];
        *(short8*)&Bs[bnn][bk0]   = *(short8*)&bv[0];
        __syncthreads();

        short8 a0 = *(const short8*)&As[wm + l15][quad * 8];
        short8 a1 = *(const short8*)&As[wm + 16 + l15][quad * 8];
        short8 b0 = *(const short8*)&Bs[wn + l15][quad * 8];
        short8 b1 = *(const short8*)&Bs[wn + 16 + l15][quad * 8];

        acc00 = __builtin_amdgcn_mfma_f32_16x16x32_bf16(a0, b0, acc00, 0, 0, 0);
        acc01 = __builtin_amdgcn_mfma_f32_16x16x32_bf16(a0, b1, acc01, 0, 0, 0);
        acc10 = __builtin_amdgcn_mfma_f32_16x16x32_bf16(a1, b0, acc10, 0, 0, 0);
        acc11 = __builtin_amdgcn_mfma_f32_16x16x32_bf16(a1, b1, acc11, 0, 0, 0);
        __syncthreads();
    }

#pragma unroll
    for (int r = 0; r < 4; ++r) {
        int row0 = bm + wm + quad * 4 + r;
        int row1 = row0 + 16;
        int col0 = bn + wn + l15;
        st_c(C + (size_t)row0 * N + col0,      acc00[r]);
        st_c(C + (size_t)row0 * N + col0 + 16, acc01[r]);
        st_c(C + (size_t)row1 * N + col0,      acc10[r]);
        st_c(C + (size_t)row1 * N + col0 + 16, acc11[r]);
    }
}

// ---------------------------------------------------------------------------
// RoPE for K + copy of V (qkv row stride parameterized).
// ---------------------------------------------------------------------------
__global__ void rope_kv(const u16* __restrict__ qkv, int QP,
                        u16* __restrict__ Kr,
                        u16* __restrict__ Vo)
{
    int idx = blockIdx.x * 256 + threadIdx.x;  // over S_LEN * 128
    int s = idx >> 7;
    int c = idx & 127;
    if (c < HDIM) {
        int d = c;
        float x  = bf2f(qkv[(size_t)s * QP + HSZ + d]);
        int dp   = (d < 32) ? d + 32 : d - 32;
        float xp = bf2f(qkv[(size_t)s * QP + HSZ + dp]);
        float rot = (d < 32) ? -xp : xp;
        float invf = expf(-(float)(d & 31) * 0.28782313662425572f);
        float ang  = (float)s * invf;
        float o = x * cosf(ang) + rot * sinf(ang);
        Kr[(size_t)s * HDIM + d] = f2bf(o);
    } else {
        int d = c - HDIM;
        Vo[(size_t)s * HDIM + d] = qkv[(size_t)s * QP + (NHEADS + 1) * HDIM + d];
    }
}

// ---------------------------------------------------------------------------
// Fused causal attention (verified R5). qkv row stride parameterized.
// ---------------------------------------------------------------------------
__global__ __launch_bounds__(256) void attn_fused(const u16* __restrict__ qkv, int QP,
                                                  const u16* __restrict__ Kr,
                                                  const u16* __restrict__ V,
                                                  u16* __restrict__ O)
{
    __shared__ u16 Kt[64][72];
    __shared__ u16 Vt[64][72];
    __shared__ u16 Ps[4][16][72];

    const int tid  = threadIdx.x;
    const int qt   = blockIdx.x;
    const int h    = blockIdx.y;
    const int qs   = qt * 64;
    const int w    = tid >> 6;
    const int lane = tid & 63;
    const int l15  = lane & 15;
    const int quad = lane >> 4;

    const int srow_a = qs + w * 16 + l15;
    const u16* qp = qkv + (size_t)srow_a * QP + h * HDIM;
    short8 r0 = *(const short8*)(qp + quad * 8);
    short8 r1 = *(const short8*)(qp + 32 + quad * 8);
    short8 qf0, qf1;
#pragma unroll
    for (int j = 0; j < 8; ++j) {
        int d0 = quad * 8 + j;
        float invf = expf(-(float)d0 * 0.28782313662425572f);
        float ang  = (float)srow_a * invf;
        float cs = cosf(ang), sn = sinf(ang);
        float x0 = bf2f((u16)r0[j]), x1 = bf2f((u16)r1[j]);
        qf0[j] = (short)f2bf((x0 * cs - x1 * sn) * 0.125f);
        qf1[j] = (short)f2bf((x1 * cs + x0 * sn) * 0.125f);
    }

    floatx4 o0 = {0.f,0.f,0.f,0.f}, o1 = {0.f,0.f,0.f,0.f};
    floatx4 o2 = {0.f,0.f,0.f,0.f}, o3 = {0.f,0.f,0.f,0.f};
    float m_prev[4] = {-1e30f, -1e30f, -1e30f, -1e30f};
    float l_prev[4] = {0.f, 0.f, 0.f, 0.f};

    const int srow_c = qs + w * 16 + quad * 4;

    for (int kt = 0; kt <= qt; ++kt) {
        __syncthreads();
        {
            int trow = tid >> 2, ch = (tid & 3) * 16;
            const u16* kp = Kr + (size_t)(kt * 64 + trow) * HDIM + ch;
            *(short8*)&Kt[trow][ch]     = *(const short8*)(kp);
            *(short8*)&Kt[trow][ch + 8] = *(const short8*)(kp + 8);
        }
        {
            int t = tid & 63, dg = (tid >> 6) * 16;
            const u16* vp = V + (size_t)(kt * 64 + t) * HDIM + dg;
            u16 tmp[16];
            *(short8*)&tmp[0] = *(const short8*)(vp);
            *(short8*)&tmp[8] = *(const short8*)(vp + 8);
#pragma unroll
            for (int j = 0; j < 16; ++j) Vt[dg + j][t] = tmp[j];
        }
        __syncthreads();

        floatx4 sc0 = {0.f,0.f,0.f,0.f}, sc1 = {0.f,0.f,0.f,0.f};
        floatx4 sc2 = {0.f,0.f,0.f,0.f}, sc3 = {0.f,0.f,0.f,0.f};
        {
            short8 ka, kb;
            ka = *(const short8*)&Kt[l15][quad * 8];
            kb = *(const short8*)&Kt[l15][32 + quad * 8];
            sc0 = __builtin_amdgcn_mfma_f32_16x16x32_bf16(qf0, ka, sc0, 0, 0, 0);
            sc0 = __builtin_amdgcn_mfma_f32_16x16x32_bf16(qf1, kb, sc0, 0, 0, 0);
            ka = *(const short8*)&Kt[16 + l15][quad * 8];
            kb = *(const short8*)&Kt[16 + l15][32 + quad * 8];
            sc1 = __builtin_amdgcn_mfma_f32_16x16x32_bf16(qf0, ka, sc1, 0, 0, 0);
            sc1 = __builtin_amdgcn_mfma_f32_16x16x32_bf16(qf1, kb, sc1, 0, 0, 0);
            ka = *(const short8*)&Kt[32 + l15][quad * 8];
            kb = *(const short8*)&Kt[32 + l15][32 + quad * 8];
            sc2 = __builtin_amdgcn_mfma_f32_16x16x32_bf16(qf0, ka, sc2, 0, 0, 0);
            sc2 = __builtin_amdgcn_mfma_f32_16x16x32_bf16(qf1, kb, sc2, 0, 0, 0);
            ka = *(const short8*)&Kt[48 + l15][quad * 8];
            kb = *(const short8*)&Kt[48 + l15][32 + quad * 8];
            sc3 = __builtin_amdgcn_mfma_f32_16x16x32_bf16(qf0, ka, sc3, 0, 0, 0);
            sc3 = __builtin_amdgcn_mfma_f32_16x16x32_bf16(qf1, kb, sc3, 0, 0, 0);
        }

        if (kt == qt) {
            int tbase = kt * 64 + l15;
#pragma unroll
            for (int r = 0; r < 4; ++r) {
                int srow = srow_c + r;
                if (tbase      > srow) sc0[r] = -1e30f;
                if (tbase + 16 > srow) sc1[r] = -1e30f;
                if (tbase + 32 > srow) sc2[r] = -1e30f;
                if (tbase + 48 > srow) sc3[r] = -1e30f;
            }
        }

        float mnew[4], al[4];
#pragma unroll
        for (int r = 0; r < 4; ++r) {
            float t0 = fmaxf(fmaxf(sc0[r], sc1[r]), fmaxf(sc2[r], sc3[r]));
            t0 = fmaxf(t0, __shfl_xor(t0, 1, 64));
            t0 = fmaxf(t0, __shfl_xor(t0, 2, 64));
            t0 = fmaxf(t0, __shfl_xor(t0, 4, 64));
            t0 = fmaxf(t0, __shfl_xor(t0, 8, 64));
            mnew[r] = fmaxf(m_prev[r], t0);
            al[r]   = __expf(m_prev[r] - mnew[r]);
        }
#pragma unroll
        for (int r = 0; r < 4; ++r) {
            float p0 = __expf(sc0[r] - mnew[r]);
            float p1 = __expf(sc1[r] - mnew[r]);
            float p2 = __expf(sc2[r] - mnew[r]);
            float p3 = __expf(sc3[r] - mnew[r]);
            Ps[w][quad * 4 + r][l15]      = f2bf(p0);
            Ps[w][quad * 4 + r][16 + l15] = f2bf(p1);
            Ps[w][quad * 4 + r][32 + l15] = f2bf(p2);
            Ps[w][quad * 4 + r][48 + l15] = f2bf(p3);
            float ls = p0 + p1 + p2 + p3;
            ls += __shfl_xor(ls, 1, 64);
            ls += __shfl_xor(ls, 2, 64);
            ls += __shfl_xor(ls, 4, 64);
            ls += __shfl_xor(ls, 8, 64);
            l_prev[r] = l_prev[r] * al[r] + ls;
            o0[r] *= al[r]; o1[r] *= al[r]; o2[r] *= al[r]; o3[r] *= al[r];
        }

        {
            short8 p0 = *(const short8*)&Ps[w][l15][quad * 8];
            short8 p1 = *(const short8*)&Ps[w][l15][32 + quad * 8];
            short8 v0, v1;
            v0 = *(const short8*)&Vt[l15][quad * 8];
            v1 = *(const short8*)&Vt[l15][32 + quad * 8];
            o0 = __builtin_amdgcn_mfma_f32_16x16x32_bf16(p0, v0, o0, 0, 0, 0);
            o0 = __builtin_amdgcn_mfma_f32_16x16x32_bf16(p1, v1, o0, 0, 0, 0);
            v0 = *(const short8*)&Vt[16 + l15][quad * 8];
            v1 = *(const short8*)&Vt[16 + l15][32 + quad * 8];
            o1 = __builtin_amdgcn_mfma_f32_16x16x32_bf16(p0, v0, o1, 0, 0, 0);
            o1 = __builtin_amdgcn_mfma_f32_16x16x32_bf16(p1, v1, o1, 0, 0, 0);
            v0 = *(const short8*)&Vt[32 + l15][quad * 8];
            v1 = *(const short8*)&Vt[32 + l15][32 + quad * 8];
            o2 = __builtin_amdgcn_mfma_f32_16x16x32_bf16(p0, v0, o2, 0, 0, 0);
            o2 = __builtin_amdgcn_mfma_f32_16x16x32_bf16(p1, v1, o2, 0, 0, 0);
            v0 = *(const short8*)&Vt[48 + l15][quad * 8];
            v1 = *(const short8*)&Vt[48 + l15][32 + quad * 8];
            o3 = __builtin_amdgcn_mfma_f32_16x16x32_bf16(p0, v0, o3, 0, 0, 0);
            o3 = __builtin_amdgcn_mfma_f32_16x16x32_bf16(p1, v1, o3, 0, 0, 0);
        }

#pragma unroll
        for (int r = 0; r < 4; ++r) m_prev[r] = mnew[r];
    }

#pragma unroll
    for (int r = 0; r < 4; ++r) {
        float inv = 1.0f / l_prev[r];
        int row = srow_c + r;
        u16* op = O + (size_t)row * HSZ + h * HDIM;
        op[l15]      = f2bf(o0[r] * inv);
        op[16 + l15] = f2bf(o1[r] * inv);
        op[32 + l15] = f2bf(o2[r] * inv);
        op[48 + l15] = f2bf(o3[r] * inv);
    }
}

// ---------------------------------------------------------------------------
extern "C" void kernel_launch(void* const* d_in, const int* in_sizes, int n_in,
                              void* d_out, int out_size, void* d_ws, size_t ws_size,
                              hipStream_t stream)
{
    const float* x       = (const float*)d_in[0];
    const float* qkv_w   = (const float*)d_in[2];
    const float* dense_w = (const float*)d_in[3];
    for (int i = 0; i < n_in; ++i) {
        if (in_sizes[i] == S_LEN * HSZ)      x       = (const float*)d_in[i];
        else if (in_sizes[i] == HSZ * QKVN)  qkv_w   = (const float*)d_in[i];
        else if (in_sizes[i] == HSZ * HSZ)   dense_w = (const float*)d_in[i];
    }
    float* out = (float*)d_out;

    // Fast-path workspace (u16 elems):
    //  xb_at : 2048*4544      (x-bf16, later reused as attn output)
    //  wt    : 4736*4544      (wq^T, later reused as wd^T)
    //  qkvp  : 2048*4736
    //  kr,vb : 2048*64 each
    const size_t E_XB  = (size_t)S_LEN * HSZ;
    const size_t E_WT  = (size_t)QKVP * HSZ;
    const size_t E_QKV = (size_t)S_LEN * QKVP;
    const size_t E_KV  = (size_t)S_LEN * HDIM;
    const size_t FAST_BYTES = (E_XB + E_WT + E_QKV + 2 * E_KV) * 2;

    if (ws_size >= FAST_BYTES) {
        u16* xb_at = (u16*)d_ws;
        u16* wt    = xb_at + E_XB;
        u16* qkvp  = wt + E_WT;
        u16* kr    = qkvp + E_QKV;
        u16* vb    = kr + E_KV;

        // x -> bf16 ; qkv_w -> bf16 transposed+padded [4736][4544]
        convert_bf16<<<(int)(E_XB / 8 / 256), 256, 0, stream>>>(x, xb_at, (int)E_XB);
        conv_transpose<<<dim3(HSZ / 32, QKVP / 32), 256, 0, stream>>>(qkv_w, wt, HSZ, QKVN);
        // QKV GEMM: [2048,4544] x [4544,4672] -> qkvp (stride 4736)
        gemm128<false><<<dim3(QKVP / 128, S_LEN / 128), 256, 0, stream>>>(
            xb_at, wt, qkvp, S_LEN, HSZ, QKVP, QKVN);
        // dense_w -> bf16 transposed+padded [4608][4544] (reuses wt)
        conv_transpose<<<dim3(HSZ / 32, DNP / 32), 256, 0, stream>>>(dense_w, wt, HSZ, HSZ);
        rope_kv<<<(S_LEN * 2 * HDIM) / 256, 256, 0, stream>>>(qkvp, QKVP, kr, vb);
        // attention output overwrites xb_at (x-bf16 is dead after QKV GEMM)
        attn_fused<<<dim3(S_LEN / 64, NHEADS), 256, 0, stream>>>(qkvp, QKVP, kr, vb, xb_at);
        // dense GEMM: [2048,4544] x [4544,4544] -> d_out fp32 (guarded cols)
        gemm128<true><<<dim3(DNP / 128, S_LEN / 128), 256, 0, stream>>>(
            xb_at, wt, out, S_LEN, HSZ, DNP, HSZ);
    } else {
        // R5 fallback (ws needs ~38.8 MB)
        u16* qkv = (u16*)d_ws;
        u16* kr  = qkv + (size_t)S_LEN * QKVN;
        u16* vb  = kr  + E_KV;
        u16* at  = vb  + E_KV;
        gemm64<float, float, u16><<<dim3(QKVN / 64, S_LEN / 64), 256, 0, stream>>>(
            x, qkv_w, qkv, S_LEN, HSZ, QKVN);
        rope_kv<<<(S_LEN * 2 * HDIM) / 256, 256, 0, stream>>>(qkv, QKVN, kr, vb);
        attn_fused<<<dim3(S_LEN / 64, NHEADS), 256, 0, stream>>>(qkv, QKVN, kr, vb, at);
        gemm64<u16, float, float><<<dim3(HSZ / 64, S_LEN / 64), 256, 0, stream>>>(
            at, dense_w, out, S_LEN, HSZ, HSZ);
    }
}

// Round 8
// 758.322 us; speedup vs baseline: 1.6793x; 1.1995x over previous
//
#include <hip/hip_runtime.h>
#include <hip/hip_bf16.h>
#include <math.h>

#define S_LEN 2048
#define NHEADS 71
#define HDIM 64
#define HSZ (NHEADS * HDIM)        // 4544
#define QKVN ((NHEADS + 2) * HDIM) // 4672
#define QKVP 4736                  // QKVN padded to 128
#define DNP  4608                  // HSZ padded to 128

typedef unsigned short u16;
typedef __attribute__((ext_vector_type(8))) short short8;
typedef __attribute__((ext_vector_type(4))) short bfx4;   // renamed: short4 collides with HIP
typedef __attribute__((ext_vector_type(4))) float floatx4;

__device__ __forceinline__ float bf2f(u16 v) {
    unsigned u = ((unsigned)v) << 16;
    return __builtin_bit_cast(float, u);
}
__device__ __forceinline__ u16 f2bf(float f) {
    unsigned u = __builtin_bit_cast(unsigned, f);
    u += 0x7fff + ((u >> 16) & 1);   // RNE
    return (u16)(u >> 16);
}

// async global->LDS, 16B per lane (wave-uniform LDS base + lane*16)
__device__ __forceinline__ void async16(const u16* g, u16* l) {
    __builtin_amdgcn_global_load_lds(
        (const __attribute__((address_space(1))) void*)g,
        (__attribute__((address_space(3))) void*)l,
        16, 0, 0);
}

// ===========================================================================
// fp32 -> bf16 elementwise (n divisible by 8)
// ===========================================================================
__global__ __launch_bounds__(256) void convert_bf16(const float* __restrict__ src,
                                                    u16* __restrict__ dst, int n)
{
    int i = (blockIdx.x * 256 + threadIdx.x) * 8;
    if (i >= n) return;
    floatx4 a = *(const floatx4*)(src + i);
    floatx4 b = *(const floatx4*)(src + i + 4);
    u16 o[8];
#pragma unroll
    for (int j = 0; j < 4; ++j) { o[j] = f2bf(a[j]); o[4 + j] = f2bf(b[j]); }
    *(short8*)(dst + i) = *(short8*)&o[0];
}

// fp32 src[K][Ns]  ->  bf16 dst[Np][K] (transposed, rows n>=Ns zero-padded)
__global__ __launch_bounds__(256) void conv_transpose(const float* __restrict__ src,
                                                      u16* __restrict__ dst,
                                                      int K, int Ns)
{
    __shared__ float t[32][33];
    const int k0 = blockIdx.x * 32, n0 = blockIdx.y * 32;
    const int tx = threadIdx.x & 31, ty = threadIdx.x >> 5;
#pragma unroll
    for (int i = 0; i < 4; ++i) {
        int r = ty + i * 8;
        int n = n0 + tx;
        t[r][tx] = (n < Ns) ? src[(size_t)(k0 + r) * Ns + n] : 0.f;
    }
    __syncthreads();
#pragma unroll
    for (int i = 0; i < 4; ++i) {
        int rr = ty + i * 8;
        dst[(size_t)(n0 + rr) * K + k0 + tx] = f2bf(t[tx][rr]);
    }
}

// ===========================================================================
// m97-structure GEMM (unchanged, verified R6)
// ===========================================================================
template <bool STORE_F32>
__global__ __launch_bounds__(256) void gemm128(const u16* __restrict__ A,   // [M][K]
                                               const u16* __restrict__ Bt,  // [Np][K]
                                               void* __restrict__ Cv,
                                               int M, int K, int Np, int Nreal)
{
    __shared__ u16 As[128 * 64];
    __shared__ u16 Bs[128 * 64];

    const int tid  = threadIdx.x;
    const int w    = tid >> 6, lane = tid & 63;
    const int l15  = lane & 15, quad = lane >> 4;
    const int bm   = blockIdx.y * 128, bn = blockIdx.x * 128;
    const int wm   = (w >> 1) * 64, wn = (w & 1) * 64;

    floatx4 acc[4][4] = {};

    const int srow = w * 32 + (lane >> 3);
    const int scol = (lane & 7) * 8;
    const u16* Ab = A  + (size_t)(bm + srow) * K + scol;
    const u16* Bb = Bt + (size_t)(bn + srow) * K + scol;
    u16* As_w = &As[(w * 32) * 64];
    u16* Bs_w = &Bs[(w * 32) * 64];

    for (int kb = 0; kb < K; kb += 64) {
#pragma unroll
        for (int i = 0; i < 4; ++i)
            async16(Ab + (size_t)(i * 8) * K + kb, As_w + i * 8 * 64);
#pragma unroll
        for (int i = 0; i < 4; ++i)
            async16(Bb + (size_t)(i * 8) * K + kb, Bs_w + i * 8 * 64);
        __syncthreads();

#pragma unroll
        for (int kk = 0; kk < 2; ++kk) {
            short8 af[4], bfr[4];
#pragma unroll
            for (int t = 0; t < 4; ++t) {
                af[t]  = *(const short8*)&As[(wm + t * 16 + l15) * 64 + kk * 32 + quad * 8];
                bfr[t] = *(const short8*)&Bs[(wn + t * 16 + l15) * 64 + kk * 32 + quad * 8];
            }
#pragma unroll
            for (int mi = 0; mi < 4; ++mi)
#pragma unroll
                for (int ni = 0; ni < 4; ++ni)
                    acc[mi][ni] = __builtin_amdgcn_mfma_f32_16x16x32_bf16(
                        af[mi], bfr[ni], acc[mi][ni], 0, 0, 0);
        }
        __syncthreads();
    }

    if (STORE_F32) {
        float* C = (float*)Cv;
#pragma unroll
        for (int mi = 0; mi < 4; ++mi)
#pragma unroll
            for (int ni = 0; ni < 4; ++ni) {
                int col  = bn + wn + ni * 16 + l15;
                int row0 = bm + wm + mi * 16 + quad * 4;
                if (col < Nreal) {
#pragma unroll
                    for (int r = 0; r < 4; ++r)
                        C[(size_t)(row0 + r) * Nreal + col] = acc[mi][ni][r];
                }
            }
    } else {
        u16* C = (u16*)Cv;
#pragma unroll
        for (int mi = 0; mi < 4; ++mi)
#pragma unroll
            for (int ni = 0; ni < 4; ++ni) {
                int col  = bn + wn + ni * 16 + l15;
                int row0 = bm + wm + mi * 16 + quad * 4;
#pragma unroll
                for (int r = 0; r < 4; ++r)
                    C[(size_t)(row0 + r) * Np + col] = f2bf(acc[mi][ni][r]);
            }
    }
}

// ===========================================================================
// RoPE for K + V transposed to [HDIM][S_LEN]
// ===========================================================================
__global__ void rope_kv(const u16* __restrict__ qkv, int QP,
                        u16* __restrict__ Kr,   // [S][64]
                        u16* __restrict__ VT)   // [64][S]
{
    int idx = blockIdx.x * 256 + threadIdx.x;  // over S_LEN * 128
    int s = idx >> 7;
    int c = idx & 127;
    if (c < HDIM) {
        int d = c;
        float x  = bf2f(qkv[(size_t)s * QP + HSZ + d]);
        int dp   = (d < 32) ? d + 32 : d - 32;
        float xp = bf2f(qkv[(size_t)s * QP + HSZ + dp]);
        float rot = (d < 32) ? -xp : xp;
        float invf = expf(-(float)(d & 31) * 0.28782313662425572f);
        float ang  = (float)s * invf;
        float o = x * cosf(ang) + rot * sinf(ang);
        Kr[(size_t)s * HDIM + d] = f2bf(o);
    } else {
        int d = c - HDIM;
        VT[(size_t)d * S_LEN + s] = qkv[(size_t)s * QP + (NHEADS + 1) * HDIM + d];
    }
}

// ===========================================================================
// Fused causal attention v2: transposed-score formulation.
//  S^T = K·Q^T  (C rows = t, cols = q)  -> per-lane softmax state (q = lane&15)
//  O^T = V^T·P^T via 16x16x32 with upper-half-K zeroed in B (half-K trick)
// Block = (head, q-tile of 64 rows) , 4 waves x 16 q rows. 128-t chunks.
// ===========================================================================
__global__ __launch_bounds__(256) void attn2(const u16* __restrict__ qkv, int QP,
                                             const u16* __restrict__ Kr,   // [S][64]
                                             const u16* __restrict__ VT,   // [64][S]
                                             u16* __restrict__ O)          // [S][HSZ]
{
    __shared__ u16 Kt[128][72];    // [t][d]   row stride 144 B
    __shared__ u16 Vt[64][136];    // [d][t]   row stride 272 B

    const int tid  = threadIdx.x;
    const int h    = blockIdx.x;
    const int qt   = 31 - blockIdx.y;    // longest blocks dispatch first
    const int qs   = qt * 64;
    const int w    = tid >> 6;
    const int lane = tid & 63;
    const int l15  = lane & 15;
    const int quad = lane >> 4;

    // ---- Q fragments (B-operand layout: n=q=l15, k=d=quad*8+j), RoPE+scale ----
    const int q_row = qs + w * 16 + l15;
    const u16* qp = qkv + (size_t)q_row * QP + h * HDIM;
    short8 r0 = *(const short8*)(qp + quad * 8);
    short8 r1 = *(const short8*)(qp + 32 + quad * 8);
    short8 qf0, qf1;
#pragma unroll
    for (int j = 0; j < 8; ++j) {
        int d0 = quad * 8 + j;
        float invf = expf(-(float)d0 * 0.28782313662425572f);
        float ang  = (float)q_row * invf;
        float cs = cosf(ang), sn = sinf(ang);
        float x0 = bf2f((u16)r0[j]), x1 = bf2f((u16)r1[j]);
        qf0[j] = (short)f2bf((x0 * cs - x1 * sn) * 0.125f);
        qf1[j] = (short)f2bf((x1 * cs + x0 * sn) * 0.125f);
    }

    floatx4 ot0 = {0.f,0.f,0.f,0.f}, ot1 = {0.f,0.f,0.f,0.f};
    floatx4 ot2 = {0.f,0.f,0.f,0.f}, ot3 = {0.f,0.f,0.f,0.f};
    float m_p = -1e30f, l_p = 0.f;
    const int qmin_w  = qs + w * 16;
    const int nchunks = (qt + 2) >> 1;

    const int krow = tid >> 1, kcol = (tid & 1) * 32;
    const int vrow = tid >> 2, vcol = (tid & 3) * 32;

    for (int c = 0; c < nchunks; ++c) {
        const int cbase = c * 128;

        // ---- prefetch chunk to regs (overlaps prior compute), then stage ----
        const u16* kp = Kr + (size_t)(cbase + krow) * HDIM + kcol;
        short8 k0 = *(const short8*)(kp);
        short8 k1 = *(const short8*)(kp + 8);
        short8 k2 = *(const short8*)(kp + 16);
        short8 k3 = *(const short8*)(kp + 24);
        const u16* vp = VT + (size_t)vrow * S_LEN + cbase + vcol;
        short8 v0 = *(const short8*)(vp);
        short8 v1 = *(const short8*)(vp + 8);
        short8 v2 = *(const short8*)(vp + 16);
        short8 v3 = *(const short8*)(vp + 24);
        __syncthreads();
        *(short8*)&Kt[krow][kcol]      = k0;
        *(short8*)&Kt[krow][kcol + 8]  = k1;
        *(short8*)&Kt[krow][kcol + 16] = k2;
        *(short8*)&Kt[krow][kcol + 24] = k3;
        *(short8*)&Vt[vrow][vcol]      = v0;
        *(short8*)&Vt[vrow][vcol + 8]  = v1;
        *(short8*)&Vt[vrow][vcol + 16] = v2;
        *(short8*)&Vt[vrow][vcol + 24] = v3;
        __syncthreads();

        // ---- active 16-t subtiles for this wave (causal early-out) ----
        const int nsub = min(8, ((qmin_w - cbase) >> 4) + 1);

        // ---- scores S^T: rows t = cbase + s*16 + quad*4 + r, col q = l15 ----
        floatx4 sc[8];
        float tmax = -3e38f;
#pragma unroll
        for (int s = 0; s < 8; ++s) {
            if (s < nsub) {
                short8 ka = *(const short8*)&Kt[s * 16 + l15][quad * 8];
                short8 kb = *(const short8*)&Kt[s * 16 + l15][32 + quad * 8];
                floatx4 a = {0.f,0.f,0.f,0.f};
                a = __builtin_amdgcn_mfma_f32_16x16x32_bf16(ka, qf0, a, 0, 0, 0);
                a = __builtin_amdgcn_mfma_f32_16x16x32_bf16(kb, qf1, a, 0, 0, 0);
                if (cbase + s * 16 + 15 > qmin_w) {   // diagonal subtile: mask t>q
                    int tb = cbase + s * 16 + quad * 4;
#pragma unroll
                    for (int r = 0; r < 4; ++r)
                        if (tb + r > q_row) a[r] = -1e30f;
                }
                sc[s] = a;
                tmax = fmaxf(tmax, fmaxf(fmaxf(a[0], a[1]), fmaxf(a[2], a[3])));
            }
        }
        // reduce over t across quads (lanes sharing l15=q): 2 shuffles
        tmax = fmaxf(tmax, __shfl_xor(tmax, 16, 64));
        tmax = fmaxf(tmax, __shfl_xor(tmax, 32, 64));

        float mnew = fmaxf(m_p, tmax);
        float al   = __expf(m_p - mnew);
        m_p = mnew;
        ot0 *= al; ot1 *= al; ot2 *= al; ot3 *= al;

        float lsum = 0.f;
#pragma unroll
        for (int s = 0; s < 8; ++s) {
            if (s < nsub) {
                float p0 = __expf(sc[s][0] - mnew);
                float p1 = __expf(sc[s][1] - mnew);
                float p2 = __expf(sc[s][2] - mnew);
                float p3 = __expf(sc[s][3] - mnew);
                lsum += (p0 + p1) + (p2 + p3);
                short8 pb = { (short)f2bf(p0), (short)f2bf(p1),
                              (short)f2bf(p2), (short)f2bf(p3), 0, 0, 0, 0 };
                const int vc = s * 16 + quad * 4;
                bfx4 va0 = *(const bfx4*)&Vt[l15][vc];
                bfx4 va1 = *(const bfx4*)&Vt[16 + l15][vc];
                bfx4 va2 = *(const bfx4*)&Vt[32 + l15][vc];
                bfx4 va3 = *(const bfx4*)&Vt[48 + l15][vc];
                short8 a0 = { va0[0], va0[1], va0[2], va0[3], 0, 0, 0, 0 };
                short8 a1 = { va1[0], va1[1], va1[2], va1[3], 0, 0, 0, 0 };
                short8 a2 = { va2[0], va2[1], va2[2], va2[3], 0, 0, 0, 0 };
                short8 a3 = { va3[0], va3[1], va3[2], va3[3], 0, 0, 0, 0 };
                ot0 = __builtin_amdgcn_mfma_f32_16x16x32_bf16(a0, pb, ot0, 0, 0, 0);
                ot1 = __builtin_amdgcn_mfma_f32_16x16x32_bf16(a1, pb, ot1, 0, 0, 0);
                ot2 = __builtin_amdgcn_mfma_f32_16x16x32_bf16(a2, pb, ot2, 0, 0, 0);
                ot3 = __builtin_amdgcn_mfma_f32_16x16x32_bf16(a3, pb, ot3, 0, 0, 0);
            }
        }
        lsum += __shfl_xor(lsum, 16, 64);
        lsum += __shfl_xor(lsum, 32, 64);
        l_p = l_p * al + lsum;
    }

    // ---- epilogue: O^T rows d = dt*16 + quad*4 + r, col q = l15 ----
    float inv = 1.0f / l_p;
    u16* op = O + (size_t)q_row * HSZ + h * HDIM + quad * 4;
    bfx4 s0 = { (short)f2bf(ot0[0]*inv), (short)f2bf(ot0[1]*inv),
                (short)f2bf(ot0[2]*inv), (short)f2bf(ot0[3]*inv) };
    bfx4 s1 = { (short)f2bf(ot1[0]*inv), (short)f2bf(ot1[1]*inv),
                (short)f2bf(ot1[2]*inv), (short)f2bf(ot1[3]*inv) };
    bfx4 s2 = { (short)f2bf(ot2[0]*inv), (short)f2bf(ot2[1]*inv),
                (short)f2bf(ot2[2]*inv), (short)f2bf(ot2[3]*inv) };
    bfx4 s3 = { (short)f2bf(ot3[0]*inv), (short)f2bf(ot3[1]*inv),
                (short)f2bf(ot3[2]*inv), (short)f2bf(ot3[3]*inv) };
    *(bfx4*)(op)      = s0;
    *(bfx4*)(op + 16) = s1;
    *(bfx4*)(op + 32) = s2;
    *(bfx4*)(op + 48) = s3;
}

// ---------------------------------------------------------------------------
extern "C" void kernel_launch(void* const* d_in, const int* in_sizes, int n_in,
                              void* d_out, int out_size, void* d_ws, size_t ws_size,
                              hipStream_t stream)
{
    const float* x       = (const float*)d_in[0];
    const float* qkv_w   = (const float*)d_in[2];
    const float* dense_w = (const float*)d_in[3];
    for (int i = 0; i < n_in; ++i) {
        if (in_sizes[i] == S_LEN * HSZ)      x       = (const float*)d_in[i];
        else if (in_sizes[i] == HSZ * QKVN)  qkv_w   = (const float*)d_in[i];
        else if (in_sizes[i] == HSZ * HSZ)   dense_w = (const float*)d_in[i];
    }
    float* out = (float*)d_out;

    // workspace (u16 elems), peak 81.6 MB (R6 proved ws_size suffices)
    const size_t E_XB  = (size_t)S_LEN * HSZ;
    const size_t E_WT  = (size_t)QKVP * HSZ;
    const size_t E_QKV = (size_t)S_LEN * QKVP;
    const size_t E_KV  = (size_t)S_LEN * HDIM;

    u16* xb_at = (u16*)d_ws;           // x bf16, later attn output
    u16* wt    = xb_at + E_XB;         // w^T (qkv, then dense)
    u16* qkvp  = wt + E_WT;
    u16* kr    = qkvp + E_QKV;
    u16* vt    = kr + E_KV;            // V^T [64][2048]

    convert_bf16<<<(int)(E_XB / 8 / 256), 256, 0, stream>>>(x, xb_at, (int)E_XB);
    conv_transpose<<<dim3(HSZ / 32, QKVP / 32), 256, 0, stream>>>(qkv_w, wt, HSZ, QKVN);
    gemm128<false><<<dim3(QKVP / 128, S_LEN / 128), 256, 0, stream>>>(
        xb_at, wt, qkvp, S_LEN, HSZ, QKVP, QKVN);
    conv_transpose<<<dim3(HSZ / 32, DNP / 32), 256, 0, stream>>>(dense_w, wt, HSZ, HSZ);
    rope_kv<<<(S_LEN * 2 * HDIM) / 256, 256, 0, stream>>>(qkvp, QKVP, kr, vt);
    attn2<<<dim3(NHEADS, 32), 256, 0, stream>>>(qkvp, QKVP, kr, vt, xb_at);
    gemm128<true><<<dim3(DNP / 128, S_LEN / 128), 256, 0, stream>>>(
        xb_at, wt, out, S_LEN, HSZ, DNP, HSZ);
}